// Round 1
// 63.550 us; speedup vs baseline: 1.0089x; 1.0089x over previous
//
#include <hip/hip_runtime.h>
#include <math.h>

// Problem constants (from setup_inputs: N=128, P=16, S=128)
#define NB    128                 // batches
#define PP    16                  // points per polyline
#define SS    128                 // image size
#define NSEG  (PP - 1)            // 15 segments
#define KPTS  (NSEG * SS)         // 1920 interpolated points per batch
#define RAD   4                   // Gaussian truncation radius: exp(-25)=1.4e-11 negligible
#define TAPS  (2 * RAD + 1)       // 9
#define TCOLS 64                  // output columns (t) handled per block (halved redundancy vs 32)
#define HY    (TCOLS + 2 * RAD)   // 72  histogram y-window width (mult of 4)
#define HX    (SS + 1 + 2 * RAD)  // 137 histogram x rows (x in [0,128] + pad 4 each side)
#define TMPX  (SS + TAPS - 1)     // 136 tmp rows (logical x in [-4,131])
#define NTHR  512                 // threads per block (8 waves)

__device__ __forceinline__ float conv9(const float* w, const float* W) {
    float acc = 0.0f;
    #pragma unroll
    for (int d = 0; d < TAPS; ++d) acc += w[d] * W[d];
    return acc;
}

__device__ __forceinline__ float fast_tanh_pos(float x) {
    // x >= 0: tanh(x) = (1 - e^{-2x}) / (1 + e^{-2x})
    const float e = __expf(-2.0f * x);
    return (1.0f - e) / (1.0f + e);
}

// Tl column swizzle: spreads rows (stride 64 floats == bank-aligned) across
// bank groups. k = (xi>>2)&7 is distinct for the 4 s0-lanes of a wave in
// pass 2 -> 8-way conflict becomes 2-way (free). XOR on bits [4:2] keeps
// float4 alignment and stays within [0,64).
__device__ __forceinline__ int swz(int xi, int col) {
    return col ^ (((xi >> 2) & 7) << 2);
}

__global__ __launch_bounds__(NTHR) void plotline_kernel(
    const float* __restrict__ points, float* __restrict__ out)
{
    const int n   = blockIdx.x >> 1;      // batch
    const int q   = blockIdx.x & 1;       // column half
    const int y0  = q * TCOLS;            // first output column of this block
    const int tid = threadIdx.x;

    __shared__ float Hl[HX][HY];          // histogram, x-padded by RAD rows each side
    __shared__ float Tl[TMPX][TCOLS];     // after y-convolution (fully overwritten)
    __shared__ float pts[PP * 2];

    // W[j] = exp(-(j-RAD)^2), f32-correctly-rounded constants
    const float W[TAPS] = {
        1.1253517471925912e-07f,  // exp(-16)
        1.2340980408667956e-04f,  // exp(-9)
        1.8315638888734179e-02f,  // exp(-4)
        3.6787944117144233e-01f,  // exp(-1)
        1.0f,
        3.6787944117144233e-01f,
        1.8315638888734179e-02f,
        1.2340980408667956e-04f,
        1.1253517471925912e-07f
    };

    // Issue the (tiny) global load first so its latency hides under zeroing.
    if (tid < PP * 2) pts[tid] = points[n * PP * 2 + tid];

    // ---- zero histogram (float4: 137*72/4 = 2466 vec stores) ----
    {
        float4* h4 = (float4*)&Hl[0][0];
        const float4 z = make_float4(0.f, 0.f, 0.f, 0.f);
        for (int i = tid; i < (HX * HY) / 4; i += NTHR) h4[i] = z;
    }
    __syncthreads();

    // ---- histogram of rounded interpolated points ----
    // Must match numpy elementwise semantics exactly: separate RN mul/mul/add
    // (no fma contraction), then round-half-to-even. t = i/128 and 1-t are
    // exact in f32 (power-of-two denominators).
    // i-permutation (*37 mod 128, bijective) puts consecutive lanes ~19 px
    // apart along the segment -> no same-address ds_add collisions, random
    // bank spread. Histogram result is identical (order-independent +1.0).
    for (int idx = tid; idx < KPTS; idx += NTHR) {
        const int j = idx >> 7;                  // segment index 0..14
        const int i = ((idx & 127) * 37) & 127;  // permuted step 0..127
        const float t   = (float)i * (1.0f / 128.0f);
        const float omt = 1.0f - t;
        const float x0 = pts[j * 2 + 0], y0p = pts[j * 2 + 1];
        const float x1 = pts[j * 2 + 2], y1p = pts[j * 2 + 3];
        const float vx = __fadd_rn(__fmul_rn(omt, x0), __fmul_rn(t, x1));
        const float vy = __fadd_rn(__fmul_rn(omt, y0p), __fmul_rn(t, y1p));
        const int ix = (int)rintf(vx);            // round half-to-even
        const int iy = (int)rintf(vy);
        const int yy = iy - y0 + RAD;             // window-local y
        if ((unsigned)ix <= 128u && (unsigned)yy < (unsigned)HY) {
            atomicAdd(&Hl[ix + RAD][yy], 1.0f);   // ds_add_f32
        }
    }
    __syncthreads();

    // ---- pass 1: y-direction 9-tap conv, register sliding window ----
    // Each task: 4 outputs Tl[xi][tl0..tl0+3] from 12-float window (3x b128).
    // Hl row stride 72 floats (bank stride 8) -> ~2-way on reads. Writes go
    // to swizzled Tl columns (see swz()).
    for (int idx = tid; idx < TMPX * (TCOLS / 4); idx += NTHR) {
        const int xi  = idx >> 4;
        const int tl0 = (idx & 15) * 4;           // 0..60; max read col 71 < HY=72
        const float4* rp = (const float4*)&Hl[xi][tl0];
        const float4 a = rp[0], b = rp[1], c = rp[2];
        const float w[12] = {a.x, a.y, a.z, a.w, b.x, b.y, b.z, b.w, c.x, c.y, c.z, c.w};
        float4 o;
        o.x = conv9(w + 0, W);
        o.y = conv9(w + 1, W);
        o.z = conv9(w + 2, W);
        o.w = conv9(w + 3, W);
        *(float4*)&Tl[xi][swz(xi, tl0)] = o;
    }
    __syncthreads();

    // ---- pass 2: x-direction 9-tap conv on a 4x4 register tile + tanh ----
    // 512 threads = 32 (s-tiles) x 16 (tl-tiles), exactly one tile each.
    {
        const int s0  = (tid >> 4) * 4;       // 0..124
        const int tl0 = (tid & 15) * 4;       // 0..60
        float4 r[12];
        #pragma unroll
        for (int i = 0; i < 12; ++i) {
            const int xi = s0 + i;            // rows s0..s0+11 <= 135 = TMPX-1
            r[i] = *(const float4*)&Tl[xi][swz(xi, tl0)];
        }
        #pragma unroll
        for (int i = 0; i < 4; ++i) {
            float4 acc = make_float4(0.f, 0.f, 0.f, 0.f);
            #pragma unroll
            for (int d = 0; d < TAPS; ++d) {
                acc.x += r[i + d].x * W[d];
                acc.y += r[i + d].y * W[d];
                acc.z += r[i + d].z * W[d];
                acc.w += r[i + d].w * W[d];
            }
            float4 res;
            res.x = fast_tanh_pos(acc.x);
            res.y = fast_tanh_pos(acc.y);
            res.z = fast_tanh_pos(acc.z);
            res.w = fast_tanh_pos(acc.w);
            *(float4*)&out[(n * SS + s0 + i) * SS + (y0 + tl0)] = res;
        }
    }
}

extern "C" void kernel_launch(void* const* d_in, const int* in_sizes, int n_in,
                              void* d_out, int out_size, void* d_ws, size_t ws_size,
                              hipStream_t stream) {
    const float* points = (const float*)d_in[0];
    float* out = (float*)d_out;
    // 128 batches x 2 column-halves
    plotline_kernel<<<dim3(NB * 2), dim3(NTHR), 0, stream>>>(points, out);
}